// Round 1
// baseline (497.780 us; speedup 1.0000x reference)
//
#include <hip/hip_runtime.h>
#include <hip/hip_bf16.h>

// LSTM encoder: B=4096, L=512, M=H=17.
// Strategy: 256 blocks x 16 batch, 5 waves/block (one 16x16 N-tile each).
// gates(80x16) = W'(80x64) . [x|h](64x16) via mfma_f32_16x16x32_bf16 (2 K-blocks),
// bias as C operand. Weight rows interleaved row=4*j+type so each lane's 4 acc
// regs are (i,f,g,o) for one j -> lane-local epilogue, c in a single register.

namespace {
constexpr int B_TOT = 4096;
constexpr int L_SEQ = 512;
constexpr int NF    = 17;                    // features == hidden
constexpr int BS    = 16;                    // batch per block
constexpr int TPB   = 320;                   // 5 waves
constexpr int TC    = 32;                    // timesteps per staged chunk
constexpr int NCHUNK = L_SEQ / TC;           // 16
constexpr int KPAD  = 24;                    // k-pad for x_s/h_s rows (quads 0..2)
constexpr int F4_PER_ROW   = TC * NF / 4;    // 136 float4 per batch-row chunk
constexpr int F4_PER_CHUNK = BS * F4_PER_ROW;// 2176
constexpr int PF_MAX = (F4_PER_CHUNK + TPB - 1) / TPB;  // 7

constexpr int OUT_H = B_TOT * L_SEQ * NF;    // 35,651,584
constexpr int OUT_C = OUT_H + B_TOT * NF;
constexpr int OUT_X = OUT_C + B_TOT * NF;
}

typedef __attribute__((ext_vector_type(8))) short bf16x8;
typedef __attribute__((ext_vector_type(4))) float f32x4;

__device__ __forceinline__ unsigned short f2bf(float f) {
  union { float f; unsigned int u; } v; v.f = f;
  unsigned int r = v.u + 0x7fff + ((v.u >> 16) & 1);   // RNE
  return (unsigned short)(r >> 16);
}
__device__ __forceinline__ float sigm(float x) {
  return __builtin_amdgcn_rcpf(1.f + __expf(-x));
}
__device__ __forceinline__ float tanh_fast(float x) {
  float e = __expf(2.f * x);                 // exp overflow -> inf -> rcp -> 0: safe
  return 1.f - 2.f * __builtin_amdgcn_rcpf(e + 1.f);
}

__global__ void __launch_bounds__(TPB) lstm_kernel(
    const float* __restrict__ x, const float* __restrict__ W_ih,
    const float* __restrict__ W_hh, const float* __restrict__ b_ih,
    const float* __restrict__ b_hh, float* __restrict__ out)
{
  __shared__ __align__(16) unsigned short x_s[2][TC][BS][KPAD]; // bf16 bits, 48 KiB
  __shared__ __align__(16) unsigned short h_s[2][BS][KPAD];     // bf16 bits
  __shared__ __align__(16) unsigned short w0_s[80][32];         // W_ih', interleaved rows
  __shared__ __align__(16) unsigned short w1_s[80][32];         // W_hh'
  __shared__ __align__(16) float bias_s[80];
  __shared__ __align__(16) unsigned short zero16[8];            // zero frag for quad 3

  const int tid  = threadIdx.x;
  const int lane = tid & 63;
  const int T    = tid >> 6;        // wave id == N-tile id
  const int bb   = lane & 15;       // batch within block (B-frag n, C col)
  const int q    = lane >> 4;       // quad (k-octet for A/B frags, row-quad for C)
  const int b0   = blockIdx.x * BS;

  // ---- prefetch chunk 0 into registers (issue ASAP)
  f32x4 pf[PF_MAX];
  #pragma unroll
  for (int i = 0; i < PF_MAX; ++i) {
    int u = tid + TPB * i;
    if (u < F4_PER_CHUNK) {
      int row = u / F4_PER_ROW, off = u % F4_PER_ROW;
      pf[i] = *(const f32x4*)(x + ((b0 + row) * L_SEQ) * NF + off * 4);
    }
  }

  // ---- zero LDS (x_s pads persist; h0=c0=0)
  {
    unsigned int* p = (unsigned int*)&x_s[0][0][0][0];
    for (int u = tid; u < (int)(sizeof(x_s) / 4); u += TPB) p[u] = 0;
    unsigned int* ph = (unsigned int*)&h_s[0][0][0];
    for (int u = tid; u < (int)(sizeof(h_s) / 4); u += TPB) ph[u] = 0;
    if (tid < 4) ((unsigned int*)zero16)[tid] = 0;
  }
  // ---- build interleaved weight tiles + fused bias
  for (int u = tid; u < 80 * 32; u += TPB) {
    int r = u >> 5, k = u & 31;
    unsigned short v0 = 0, v1 = 0;
    int j = -1, ty = 0;
    if (r < 64)      { j = r >> 2; ty = r & 3; }
    else if (r < 68) { j = 16;     ty = r - 64; }
    if (j >= 0 && k < NF) {
      int g = ty * NF + j;          // torch gate order i,f,g,o
      v0 = f2bf(W_ih[g * NF + k]);
      v1 = f2bf(W_hh[g * NF + k]);
    }
    w0_s[r][k] = v0; w1_s[r][k] = v1;
  }
  for (int u = tid; u < 80; u += TPB) {
    float bv = 0.f; int j = -1, ty = 0;
    if (u < 64)      { j = u >> 2; ty = u & 3; }
    else if (u < 68) { j = 16;     ty = u - 64; }
    if (j >= 0) { int g = ty * NF + j; bv = b_ih[g] + b_hh[g]; }
    bias_s[u] = bv;
  }
  __syncthreads();   // zero-init & weights visible before staging/frag reads

  // ---- stage helper: write pf (chunk cn) to x_s[cn&1] + passthrough x copy
  auto stage = [&](int cn) {
    #pragma unroll
    for (int i = 0; i < PF_MAX; ++i) {
      int u = tid + TPB * i;
      if (u < F4_PER_CHUNK) {
        int row = u / F4_PER_ROW, off = u % F4_PER_ROW;
        int gidx = ((b0 + row) * L_SEQ + cn * TC) * NF + off * 4;
        *(f32x4*)(out + OUT_X + gidx) = pf[i];
        int p = off * 4, tl = p / NF, m = p - tl * NF;
        #pragma unroll
        for (int e = 0; e < 4; ++e) {
          x_s[cn & 1][tl][row][m] = f2bf(pf[i][e]);
          if (++m == NF) { m = 0; ++tl; }
        }
      }
    }
  };
  auto prefetch = [&](int cn) {
    #pragma unroll
    for (int i = 0; i < PF_MAX; ++i) {
      int u = tid + TPB * i;
      if (u < F4_PER_CHUNK) {
        int row = u / F4_PER_ROW, off = u % F4_PER_ROW;
        pf[i] = *(const f32x4*)(x + ((b0 + row) * L_SEQ + cn * TC) * NF + off * 4);
      }
    }
  };

  stage(0);        // writes buf 0; visible after first in-loop barrier
  prefetch(1);

  // ---- per-wave constant fragments (weights + bias), per-lane pointers
  const bf16x8 a0 = *(const bf16x8*)&w0_s[16 * T + bb][q * 8];
  const bf16x8 a1 = *(const bf16x8*)&w1_s[16 * T + bb][q * 8];
  const f32x4 bias4 = *(const f32x4*)&bias_s[16 * T + q * 4];

  const int j = 4 * T + q;                       // hidden index owned by this lane
  const bool active = (T < 4) || (q == 0);       // tile 4: only j=16 (quad 0) real
  const int jj = (j > 16) ? 16 : j;              // clamp for safe address formation

  const unsigned short* xbuf[2] = {
    (q == 3) ? zero16 : &x_s[0][0][bb][q * 8],
    (q == 3) ? zero16 : &x_s[1][0][bb][q * 8] };
  const int xstep = (q == 3) ? 0 : BS * KPAD;    // ushorts per timestep
  const unsigned short* hr[2] = {
    (q == 3) ? zero16 : &h_s[0][bb][q * 8],
    (q == 3) ? zero16 : &h_s[1][bb][q * 8] };
  unsigned short* hw[2] = { &h_s[1][bb][jj], &h_s[0][bb][jj] };  // write buf (t+1)&1

  float c_st = 0.f, h_last = 0.f;
  float* outp = out + (b0 + bb) * L_SEQ * NF + jj;

  // ---- main recurrence
  for (int c = 0; c < NCHUNK; ++c) {
    const unsigned short* xp = xbuf[c & 1];
    for (int tt = 0; tt < TC; ++tt) {
      const int t = c * TC + tt;
      __syncthreads();                           // h_s[t&1] & staged x_s ready
      bf16x8 bx = *(const bf16x8*)xp;
      bf16x8 bh = *(const bf16x8*)hr[t & 1];
      xp += xstep;
      f32x4 acc = __builtin_amdgcn_mfma_f32_16x16x32_bf16(a0, bx, bias4, 0, 0, 0);
      acc       = __builtin_amdgcn_mfma_f32_16x16x32_bf16(a1, bh, acc,   0, 0, 0);
      if (active) {
        float gi = sigm(acc[0]);
        float gf = sigm(acc[1]);
        float gg = tanh_fast(acc[2]);
        float go = sigm(acc[3]);
        c_st  = gf * c_st + gi * gg;
        h_last = go * tanh_fast(c_st);
        *hw[t & 1] = f2bf(h_last);
        outp[0] = h_last;
        outp += NF;
      }
    }
    if (c + 1 < NCHUNK) {
      stage(c + 1);                              // other x buffer: no race with step 31
      if (c + 2 < NCHUNK) prefetch(c + 2);
    }
  }

  // ---- final states
  if (active) {
    out[OUT_H + (b0 + bb) * NF + j] = h_last;
    out[OUT_C + (b0 + bb) * NF + j] = c_st;
  }
}

extern "C" void kernel_launch(void* const* d_in, const int* in_sizes, int n_in,
                              void* d_out, int out_size, void* d_ws, size_t ws_size,
                              hipStream_t stream) {
  (void)in_sizes; (void)n_in; (void)out_size; (void)d_ws; (void)ws_size;
  const float* x    = (const float*)d_in[0];
  const float* W_ih = (const float*)d_in[1];
  const float* W_hh = (const float*)d_in[2];
  const float* b_ih = (const float*)d_in[3];
  const float* b_hh = (const float*)d_in[4];
  float* out = (float*)d_out;
  hipLaunchKernelGGL(lstm_kernel, dim3(B_TOT / BS), dim3(TPB), 0, stream,
                     x, W_ih, W_hh, b_ih, b_hh, out);
}